// Round 2
// baseline (1647.998 us; speedup 1.0000x reference)
//
#include <hip/hip_runtime.h>
#include <hip/hip_bf16.h>

// R5: gemm_qkv = latency-bound on random embed-row gather (R4 post-mortem:
// conflicts->0, LDS bytes down, yet dur up; nothing saturated). Two fixes:
// (1) depth-2 pipeline: A reg-loads + B global_load_lds for tile t+2 issued
//     at phase t; LDS double-buffered; waits are counted vmcnt(6), never 0.
// (2) XCD-bijective block swizzle: all 24 n-tiles of an m-tile on ONE XCD
//     (co-resident on its 32 CUs) -> gathered A rows hit that XCD's L2
//     instead of being re-fetched from HBM by 8 XCDs (FETCH 1.6GB -> ~0.5GB).
// attn / gemm_out_logits / loss unchanged.

typedef __attribute__((ext_vector_type(8))) short short8;   // 8 x bf16
typedef __attribute__((ext_vector_type(4))) float f32x4;

#define GLB_AS __attribute__((address_space(1)))
#define LDS_AS __attribute__((address_space(3)))

__device__ __forceinline__ float b2f(unsigned short u) {
    union { unsigned int i; float f; } v; v.i = ((unsigned int)u) << 16; return v.f;
}
__device__ __forceinline__ unsigned short f2b(float f) {
    union { float f; unsigned int i; } v; v.f = f;
    unsigned int u = v.i;
    u += 0x7fffu + ((u >> 16) & 1u);   // RNE
    return (unsigned short)(u >> 16);
}
__device__ __forceinline__ unsigned int fbits(float f) {
    union { float f; unsigned int i; } v; v.f = f; return v.i;
}
// pack hi16(a0..a3,b0..b3) -> short8 bf16 (RTZ truncation), via v_perm_b32
__device__ __forceinline__ short8 pack_bf16_rtz(f32x4 a, f32x4 b) {
    union { unsigned int u[4]; short8 s; } r;
    r.u[0] = __builtin_amdgcn_perm(fbits(a[1]), fbits(a[0]), 0x07060302u);
    r.u[1] = __builtin_amdgcn_perm(fbits(a[3]), fbits(a[2]), 0x07060302u);
    r.u[2] = __builtin_amdgcn_perm(fbits(b[1]), fbits(b[0]), 0x07060302u);
    r.u[3] = __builtin_amdgcn_perm(fbits(b[3]), fbits(b[2]), 0x07060302u);
    return r.s;
}

__device__ __forceinline__ void gload_lds16(const void* src, void* ldsDst) {
    // 16B/lane async global->LDS; LDS dest = wave-uniform base + lane*16
    __builtin_amdgcn_global_load_lds((const GLB_AS void*)src, (LDS_AS void*)ldsDst, 16, 0, 0);
}

// ---------------------------------------------------------------------------
// Transpose fp32 [rows][cols] -> bf16 [cols][rows]  (weights to B^T=[N][K])
// ---------------------------------------------------------------------------
__global__ __launch_bounds__(256) void transpose_f32_bf16(
    const float* __restrict__ in, unsigned short* __restrict__ out,
    int rows, int cols)
{
    __shared__ float tile[32][33];
    const int c0 = blockIdx.x << 5, r0 = blockIdx.y << 5;
    const int tx = threadIdx.x, ty = threadIdx.y;
#pragma unroll
    for (int rr = ty; rr < 32; rr += 8)
        tile[rr][tx] = in[(size_t)(r0 + rr) * cols + (c0 + tx)];
    __syncthreads();
#pragma unroll
    for (int rr = ty; rr < 32; rr += 8)
        out[(size_t)(c0 + rr) * rows + (r0 + tx)] = f2b(tile[tx][rr]);
}

__global__ void zero_logits(float* __restrict__ logits) {
    logits[threadIdx.x] = 0.0f;   // 64 floats
}

// ---------------------------------------------------------------------------
// GEMM1: qkv[m][n] = sum_k embed[x[m]][k] * WT[n][k]  (M=65536,N=3072,K=1024)
// Depth-2 pipeline, dbuf LDS, counted vmcnt(6). Phase t (parity C):
//   frag ds_read As[C],Bs[C]; lgkm(0); barrier;
//   issue A(t+2)->pa[C] regs + B(t+2)->Bs[C] gload_lds;   (6 vmem ops/phase)
//   MFMA tile t; vmcnt(6) [=> tile t+1 loads landed];
//   cvt+ds_write As[C^1] <- pa[C^1]; lgkm(0); barrier.
// OOB prefetch at t=30,31 reads spill into adjacent rows (allocated, unused).
// ---------------------------------------------------------------------------
__global__ __launch_bounds__(256) void gemm_qkv(
    const int* __restrict__ x, const float* __restrict__ embed,
    const unsigned short* __restrict__ WT, unsigned short* __restrict__ qkv)
{
    __shared__ __align__(16) unsigned short As[2][4096];   // 2 x 8KB bf16
    __shared__ __align__(16) unsigned short Bs[2][4096];   // 2 x 8KB bf16
    __shared__ int xs[128];

    const int tid = threadIdx.x;
    const int lane = tid & 63;
    const int wv = tid >> 6;
    const int wm = wv >> 1, wn = wv & 1;

    // XCD-bijective swizzle: nwg = 24*512 = 12288, 12288 % 8 == 0.
    // XCD k gets wgid in [k*1536,(k+1)*1536) = m-tiles [k*64,(k+1)*64),
    // each m-tile's 24 n-blocks co-resident on that XCD -> A rows L2-hit.
    const int fid = blockIdx.y * 24 + blockIdx.x;
    const int wg  = (fid & 7) * 1536 + (fid >> 3);
    const int m0 = (wg / 24) << 7;
    const int n0 = (wg % 24) << 7;
    const int r = lane & 15, q4 = lane >> 4;

    if (tid < 128) xs[tid] = x[m0 + tid];
    __syncthreads();

    // A staging ownership: thread t -> row = t>>1, half h = t&1 (16 floats)
    const int arow = tid >> 1, ah = tid & 1;
    const int aswz = (arow >> 1) & 3;
    const float* srcA = embed + (size_t)xs[arow] * 1024 + ah * 16;
    unsigned short* dstA0[2];
    unsigned short* dstA1[2];
#pragma unroll
    for (int b = 0; b < 2; ++b) {
        dstA0[b] = &As[b][0] + (size_t)(arow * 4 + ((2 * ah) ^ aswz)) * 8;
        dstA1[b] = &As[b][0] + (size_t)(arow * 4 + ((2 * ah + 1) ^ aswz)) * 8;
    }

    // B staging sources (per-lane), slot = wv*128 + t*64 + lane
    const unsigned short* baseB0;
    const unsigned short* baseB1;
    {
        int slot0 = wv * 128 + lane;
        int row0 = slot0 >> 2;
        int g0 = (slot0 & 3) ^ ((row0 >> 1) & 3);
        baseB0 = WT + (((size_t)(n0 + row0)) << 10) + g0 * 8;
        int slot1 = wv * 128 + 64 + lane;
        int row1 = slot1 >> 2;
        int g1 = (slot1 & 3) ^ ((row1 >> 1) & 3);
        baseB1 = WT + (((size_t)(n0 + row1)) << 10) + g1 * 8;
    }

    f32x4 acc[4][4];
#pragma unroll
    for (int i = 0; i < 4; ++i)
#pragma unroll
        for (int j = 0; j < 4; ++j) acc[i][j] = (f32x4){0.f, 0.f, 0.f, 0.f};

    f32x4 pa0_0, pa0_1, pa0_2, pa0_3;   // A regs, even tiles
    f32x4 pa1_0, pa1_1, pa1_2, pa1_3;   // A regs, odd tiles

    // ---- prologue: tiles 0 and 1 in flight, tile 0 committed to LDS ----
    pa0_0 = *(const f32x4*)(srcA + 0);
    pa0_1 = *(const f32x4*)(srcA + 4);
    pa0_2 = *(const f32x4*)(srcA + 8);
    pa0_3 = *(const f32x4*)(srcA + 12);
    gload_lds16(baseB0 + 0, &Bs[0][0] + (size_t)(wv * 128) * 8);
    gload_lds16(baseB1 + 0, &Bs[0][0] + (size_t)(wv * 128 + 64) * 8);
    __asm__ volatile("" ::: "memory");   // group fence: tile0's 6 vmem first
    pa1_0 = *(const f32x4*)(srcA + 32);
    pa1_1 = *(const f32x4*)(srcA + 36);
    pa1_2 = *(const f32x4*)(srcA + 40);
    pa1_3 = *(const f32x4*)(srcA + 44);
    gload_lds16(baseB0 + 32, &Bs[1][0] + (size_t)(wv * 128) * 8);
    gload_lds16(baseB1 + 32, &Bs[1][0] + (size_t)(wv * 128 + 64) * 8);
    __asm__ volatile("s_waitcnt vmcnt(6)" ::: "memory");   // tile0 A+B landed
    *(short8*)dstA0[0] = pack_bf16_rtz(pa0_0, pa0_1);
    *(short8*)dstA1[0] = pack_bf16_rtz(pa0_2, pa0_3);
    __asm__ volatile("s_waitcnt lgkmcnt(0)" ::: "memory");
    __builtin_amdgcn_s_barrier();

#define QKV_PHASE(C, OC, PA, PB, KTN)                                          \
  {                                                                            \
    short8 af[4], bfr[4];                                                      \
    _Pragma("unroll")                                                          \
    for (int i = 0; i < 4; ++i) {                                              \
      int lrow = wm * 64 + i * 16 + r;                                         \
      int slot = lrow * 4 + (q4 ^ ((lrow >> 1) & 3));                          \
      af[i] = *(const short8*)(&As[C][0] + (size_t)slot * 8);                  \
    }                                                                          \
    _Pragma("unroll")                                                          \
    for (int j = 0; j < 4; ++j) {                                              \
      int lrow = wn * 64 + j * 16 + r;                                         \
      int slot = lrow * 4 + (q4 ^ ((lrow >> 1) & 3));                          \
      bfr[j] = *(const short8*)(&Bs[C][0] + (size_t)slot * 8);                 \
    }                                                                          \
    __asm__ volatile("s_waitcnt lgkmcnt(0)" ::: "memory");                     \
    __builtin_amdgcn_s_barrier();                                              \
    PA##_0 = *(const f32x4*)(srcA + (KTN));                                    \
    PA##_1 = *(const f32x4*)(srcA + (KTN) + 4);                                \
    PA##_2 = *(const f32x4*)(srcA + (KTN) + 8);                                \
    PA##_3 = *(const f32x4*)(srcA + (KTN) + 12);                               \
    gload_lds16(baseB0 + (KTN), &Bs[C][0] + (size_t)(wv * 128) * 8);           \
    gload_lds16(baseB1 + (KTN), &Bs[C][0] + (size_t)(wv * 128 + 64) * 8);      \
    __builtin_amdgcn_sched_barrier(0);                                         \
    _Pragma("unroll")                                                          \
    for (int i = 0; i < 4; ++i)                                                \
      _Pragma("unroll")                                                        \
      for (int j = 0; j < 4; ++j)                                              \
        acc[i][j] = __builtin_amdgcn_mfma_f32_16x16x32_bf16(af[i], bfr[j],     \
                                                            acc[i][j], 0, 0, 0);\
    __asm__ volatile("s_waitcnt vmcnt(6)" ::: "memory");                       \
    *(short8*)dstA0[OC] = pack_bf16_rtz(PB##_0, PB##_1);                       \
    *(short8*)dstA1[OC] = pack_bf16_rtz(PB##_2, PB##_3);                       \
    __builtin_amdgcn_sched_barrier(0);                                         \
    __asm__ volatile("s_waitcnt lgkmcnt(0)" ::: "memory");                     \
    __builtin_amdgcn_s_barrier();                                              \
  }

    for (int kb = 0; kb < 1024; kb += 64) {
        QKV_PHASE(0, 1, pa0, pa1, kb + 64)    // tile kb/32   (even), prefetch t+2
        QKV_PHASE(1, 0, pa1, pa0, kb + 96)    // tile kb/32+1 (odd),  prefetch t+2
    }
#undef QKV_PHASE

    // epilogue: C/D layout col=lane&15, row=q4*4+reg (m89-verified)
#pragma unroll
    for (int i = 0; i < 4; ++i) {
        int lmb = wm * 64 + i * 16 + q4 * 4;
#pragma unroll
        for (int j = 0; j < 4; ++j) {
            int ln = n0 + wn * 64 + j * 16 + r;
#pragma unroll
            for (int rg = 0; rg < 4; ++rg) {
                int m = m0 + lmb + rg;
                qkv[(size_t)m * 3072 + ln] = f2b(acc[i][j][rg]);
            }
        }
    }
}

// ---------------------------------------------------------------------------
// Attention over the batch dim. 1 wave per (l, head). qkv rows m=b*2048+l,
// cols: q=[0,1024) k=[1024,2048) v=[2048,3072), head slab nh*64+d.
// S=QK^T (8 mfma), softmax over j in-registers (16-lane shfl), P->LDS->A-frag,
// V^T in LDS, PV (8 mfma). att overwrites the q slab in place.
// ---------------------------------------------------------------------------
__global__ __launch_bounds__(256) void attn(unsigned short* __restrict__ qkv)
{
    __shared__ __align__(16) unsigned short Vt[4][64 * 40]; // per-wave V^T [d][j], pad 40
    __shared__ __align__(16) unsigned short Ps[4][32 * 40]; // per-wave P [i][j], pad 40
    const int tid = threadIdx.x, lane = tid & 63, wv = tid >> 6;
    const int flat = (blockIdx.x << 2) + wv;     // 0..32767
    const int l = flat >> 4, nh = flat & 15;
    const int r = lane & 15, q4 = lane >> 4;
    const size_t ROWB = (size_t)2048 * 3072;     // batch stride in elements

    unsigned short* vt = Vt[wv];
    unsigned short* ps = Ps[wv];

    unsigned short* qb = qkv + (size_t)l * 3072 + nh * 64;
    const unsigned short* kb = qb + 1024;
    const unsigned short* vb = qb + 2048;

    // stage V^T: lane=d, pack (j,j+1) into a dword -> conflict-free b32 writes
#pragma unroll
    for (int p = 0; p < 16; ++p) {
        unsigned short v0 = vb[(size_t)(2 * p) * ROWB + lane];
        unsigned short v1 = vb[(size_t)(2 * p + 1) * ROWB + lane];
        *(unsigned int*)(vt + lane * 40 + 2 * p) = (unsigned int)v0 | ((unsigned int)v1 << 16);
    }

    // Q/K fragments straight from global: per instr 16 rows x 64B segments
    short8 aQ[2][2], bK[2][2];
#pragma unroll
    for (int it = 0; it < 2; ++it)
#pragma unroll
        for (int ks = 0; ks < 2; ++ks) {
            aQ[it][ks] = *(const short8*)(qb + (size_t)(it * 16 + r) * ROWB + ks * 32 + q4 * 8);
            bK[it][ks] = *(const short8*)(kb + (size_t)(it * 16 + r) * ROWB + ks * 32 + q4 * 8);
        }

    f32x4 S[2][2];
#pragma unroll
    for (int it = 0; it < 2; ++it)
#pragma unroll
        for (int jt = 0; jt < 2; ++jt) {
            f32x4 z = (f32x4){0.f, 0.f, 0.f, 0.f};
            z = __builtin_amdgcn_mfma_f32_16x16x32_bf16(aQ[it][0], bK[jt][0], z, 0, 0, 0);
            z = __builtin_amdgcn_mfma_f32_16x16x32_bf16(aQ[it][1], bK[jt][1], z, 0, 0, 0);
            S[it][jt] = z;
        }

    // softmax over j (row i = it*16 + q4*4 + rg; its 32 cols live in 16 lanes x 2 jt)
#pragma unroll
    for (int it = 0; it < 2; ++it)
#pragma unroll
        for (int rg = 0; rg < 4; ++rg) {
            float s0 = S[it][0][rg] * 0.125f;
            float s1 = S[it][1][rg] * 0.125f;
            float mx = fmaxf(s0, s1);
#pragma unroll
            for (int d = 1; d < 16; d <<= 1) mx = fmaxf(mx, __shfl_xor(mx, d, 64));
            float e0 = __expf(s0 - mx), e1 = __expf(s1 - mx);
            float sm = e0 + e1;
#pragma unroll
            for (int d = 1; d < 16; d <<= 1) sm += __shfl_xor(sm, d, 64);
            float inv = 1.0f / sm;
            int i = it * 16 + q4 * 4 + rg;
            ps[i * 40 + r]      = f2b(e0 * inv);
            ps[i * 40 + 16 + r] = f2b(e1 * inv);
        }

    __asm__ volatile("s_waitcnt lgkmcnt(0)" ::: "memory");  // Vt + Ps visible (same wave)

    short8 aP[2], bV[4];
#pragma unroll
    for (int it = 0; it < 2; ++it)
        aP[it] = *(const short8*)(ps + (it * 16 + r) * 40 + q4 * 8);
#pragma unroll
    for (int dt = 0; dt < 4; ++dt)
        bV[dt] = *(const short8*)(vt + (dt * 16 + r) * 40 + q4 * 8);

    f32x4 O[2][4];
#pragma unroll
    for (int it = 0; it < 2; ++it)
#pragma unroll
        for (int dt = 0; dt < 4; ++dt) {
            f32x4 z = (f32x4){0.f, 0.f, 0.f, 0.f};
            O[it][dt] = __builtin_amdgcn_mfma_f32_16x16x32_bf16(aP[it], bV[dt], z, 0, 0, 0);
        }

    // att -> q slab (in place; this wave already consumed its Q)
#pragma unroll
    for (int it = 0; it < 2; ++it)
#pragma unroll
        for (int dt = 0; dt < 4; ++dt)
#pragma unroll
            for (int rg = 0; rg < 4; ++rg) {
                int i = it * 16 + q4 * 4 + rg;
                qb[(size_t)i * ROWB + dt * 16 + r] = f2b(O[it][dt][rg]);
            }
}

// ---------------------------------------------------------------------------
// GEMM2: out[m][e] = h[m][e] + sum_k att[m][k]*WoT[e][k]; fused logits:
// logits[b][c] += sum_e out[m][e]*Wf[l*1024+e][c]. embed/Wf read as fp32.
// ---------------------------------------------------------------------------
__global__ __launch_bounds__(256) void gemm_out_logits(
    const int* __restrict__ x, const float* __restrict__ embed,
    const unsigned short* __restrict__ qkv, const unsigned short* __restrict__ WoT,
    const float* __restrict__ Wf, float* __restrict__ logits)
{
    __shared__ __align__(16) unsigned short As[4096];
    __shared__ __align__(16) unsigned short Bs[4096];
    __shared__ int xs[128];
    __shared__ float red[2];

    const int tid = threadIdx.x;
    const int lane = tid & 63;
    const int wv = tid >> 6;
    const int wm = wv >> 1, wn = wv & 1;
    const int m0 = blockIdx.y << 7;
    const int n0 = blockIdx.x << 7;
    const int r = lane & 15, q4 = lane >> 4;

    if (tid < 128) xs[tid] = x[m0 + tid];
    if (tid == 0) { red[0] = 0.f; red[1] = 0.f; }
    __syncthreads();

    const unsigned short* baseA[2];
    const unsigned short* baseB[2];
#pragma unroll
    for (int t = 0; t < 2; ++t) {
        int slot = wv * 128 + t * 64 + lane;
        int row = slot >> 2;
        int g = (slot & 3) ^ ((row >> 1) & 3);
        baseA[t] = qkv + (size_t)(m0 + row) * 3072 + g * 8;   // att in cols [0,1024)
        baseB[t] = WoT + (((size_t)(n0 + row)) << 10) + g * 8;
    }

    f32x4 acc[4][4];
#pragma unroll
    for (int i = 0; i < 4; ++i)
#pragma unroll
        for (int j = 0; j < 4; ++j) acc[i][j] = (f32x4){0.f, 0.f, 0.f, 0.f};

    for (int kt = 0; kt < 1024; kt += 32) {
        __syncthreads();
#pragma unroll
        for (int t = 0; t < 2; ++t) {
            gload_lds16(baseA[t] + kt, As + (size_t)(wv * 128 + t * 64) * 8);
            gload_lds16(baseB[t] + kt, Bs + (size_t)(wv * 128 + t * 64) * 8);
        }
        __syncthreads();

        short8 af[4], bfr[4];
#pragma unroll
        for (int i = 0; i < 4; ++i) {
            int lrow = wm * 64 + i * 16 + r;
            int slot = lrow * 4 + (q4 ^ ((lrow >> 1) & 3));
            af[i] = *(const short8*)(As + (size_t)slot * 8);
        }
#pragma unroll
        for (int j = 0; j < 4; ++j) {
            int lrow = wn * 64 + j * 16 + r;
            int slot = lrow * 4 + (q4 ^ ((lrow >> 1) & 3));
            bfr[j] = *(const short8*)(Bs + (size_t)slot * 8);
        }
#pragma unroll
        for (int i = 0; i < 4; ++i)
#pragma unroll
            for (int j = 0; j < 4; ++j)
                acc[i][j] = __builtin_amdgcn_mfma_f32_16x16x32_bf16(af[i], bfr[j], acc[i][j], 0, 0, 0);
    }

    // epilogue: residual (fp32 embed gather) + Wf (fp32) reduction
    float c0 = 0.f, c1 = 0.f;
#pragma unroll
    for (int i = 0; i < 4; ++i) {
        int lmb = wm * 64 + i * 16 + q4 * 4;
#pragma unroll
        for (int j = 0; j < 4; ++j) {
            int e = n0 + wn * 64 + j * 16 + r;
#pragma unroll
            for (int rg = 0; rg < 4; ++rg) {
                int lm = lmb + rg;
                int m = m0 + lm;
                int ll = m & 2047;
                float hv = embed[(size_t)xs[lm] * 1024 + e];
                float outv = acc[i][j][rg] + hv;
                const float* wfp = Wf + ((size_t)(ll << 10) + e) * 2;
                c0 += outv * wfp[0];
                c1 += outv * wfp[1];
            }
        }
    }
#pragma unroll
    for (int d = 1; d < 64; d <<= 1) {
        c0 += __shfl_xor(c0, d, 64);
        c1 += __shfl_xor(c1, d, 64);
    }
    __syncthreads();
    if (lane == 0) { atomicAdd(&red[0], c0); atomicAdd(&red[1], c1); }
    __syncthreads();
    if (tid == 0) {
        int b = m0 >> 11;
        atomicAdd(&logits[b * 2 + 0], red[0]);
        atomicAdd(&logits[b * 2 + 1], red[1]);
    }
}

// ---------------------------------------------------------------------------
// Loss: -mean_b( log_softmax(logits[b]+bf)[y_b] ), C=2. Output fp32 scalar.
// ---------------------------------------------------------------------------
__global__ void loss_k(const float* __restrict__ logits, const int* __restrict__ y,
                       const float* __restrict__ bfb, float* __restrict__ out)
{
    const int t = threadIdx.x;
    float contrib = 0.f;
    if (t < 32) {
        float l0 = logits[t * 2 + 0] + bfb[0];
        float l1 = logits[t * 2 + 1] + bfb[1];
        float mx = fmaxf(l0, l1);
        float lse = mx + logf(expf(l0 - mx) + expf(l1 - mx));
        float chosen = (y[t] == 0) ? l0 : l1;
        contrib = -(chosen - lse) * (1.0f / 32.0f);
    }
#pragma unroll
    for (int d = 1; d < 64; d <<= 1) contrib += __shfl_xor(contrib, d, 64);
    if (t == 0) *out = contrib;    // fp32 output
}

// ---------------------------------------------------------------------------
extern "C" void kernel_launch(void* const* d_in, const int* in_sizes, int n_in,
                              void* d_out, int out_size, void* d_ws, size_t ws_size,
                              hipStream_t stream) {
    const int* x      = (const int*)d_in[0];
    const int* y      = (const int*)d_in[1];
    const float* emb  = (const float*)d_in[2];
    const float* Wq   = (const float*)d_in[3];
    const float* Wkv  = (const float*)d_in[4];
    const float* Wo   = (const float*)d_in[5];
    const float* Wf   = (const float*)d_in[6];
    const float* bfb  = (const float*)d_in[7];

    char* ws = (char*)d_ws;
    unsigned short* qkv    = (unsigned short*)ws;                        // 384 MB bf16
    unsigned short* WqkvT  = (unsigned short*)(ws + 402653184);          // [3072][1024] bf16
    unsigned short* WoT    = (unsigned short*)(ws + 408944640);          // [1024][1024] bf16
    float*          logits = (float*)(ws + 411041792);                   // [32][2] fp32
    float*          out    = (float*)d_out;

    zero_logits<<<1, 64, 0, stream>>>(logits);

    transpose_f32_bf16<<<dim3(32, 32), dim3(32, 8), 0, stream>>>(Wq, WqkvT, 1024, 1024);
    transpose_f32_bf16<<<dim3(64, 32), dim3(32, 8), 0, stream>>>(Wkv, WqkvT + 1024 * 1024, 1024, 2048);
    transpose_f32_bf16<<<dim3(32, 32), dim3(32, 8), 0, stream>>>(Wo, WoT, 1024, 1024);

    gemm_qkv<<<dim3(24, 512), 256, 0, stream>>>(x, emb, WqkvT, qkv);
    attn<<<8192, 256, 0, stream>>>(qkv);
    gemm_out_logits<<<dim3(8, 512), 256, 0, stream>>>(x, emb, qkv, WoT, Wf, logits);
    loss_k<<<1, 64, 0, stream>>>(logits, y, bfb, out);
}

// Round 3
// 1485.706 us; speedup vs baseline: 1.1092x; 1.1092x over previous
//
#include <hip/hip_runtime.h>
#include <hip/hip_bf16.h>

// R6: R4/R5 post-mortem — in-GEMM random embed gather (400MB table >> LLC)
// is latency+miss bound and re-gathered 24x (once per n-block); neither
// reg-prefetch (R4) nor depth-2 counted-vmcnt + XCD swizzle (R5) helped
// (FETCH rose, MfmaUtil fell). Fix: hoist the gather into a streaming pass
// gather_h: h[m][k] = bf16(embed[x[m]][k])  (128 MB, LLC-resident), then
// gemm_qkv_dense = plain m97-structure GEMM with BOTH operands via
// global_load_lds (identical loop to the proven gemm_out_logits). Runtime
// ws_size check falls back to the R3 gather-fused kernel if workspace is
// too small. attn / gemm_out_logits / loss unchanged.

typedef __attribute__((ext_vector_type(8))) short short8;   // 8 x bf16
typedef __attribute__((ext_vector_type(4))) float f32x4;

#define GLB_AS __attribute__((address_space(1)))
#define LDS_AS __attribute__((address_space(3)))

__device__ __forceinline__ float b2f(unsigned short u) {
    union { unsigned int i; float f; } v; v.i = ((unsigned int)u) << 16; return v.f;
}
__device__ __forceinline__ unsigned short f2b(float f) {
    union { float f; unsigned int i; } v; v.f = f;
    unsigned int u = v.i;
    u += 0x7fffu + ((u >> 16) & 1u);   // RNE
    return (unsigned short)(u >> 16);
}
__device__ __forceinline__ unsigned int fbits(float f) {
    union { float f; unsigned int i; } v; v.f = f; return v.i;
}
// pack hi16(a0..a3,b0..b3) -> short8 bf16 (RTZ truncation), via v_perm_b32
__device__ __forceinline__ short8 pack_bf16_rtz(f32x4 a, f32x4 b) {
    union { unsigned int u[4]; short8 s; } r;
    r.u[0] = __builtin_amdgcn_perm(fbits(a[1]), fbits(a[0]), 0x07060302u);
    r.u[1] = __builtin_amdgcn_perm(fbits(a[3]), fbits(a[2]), 0x07060302u);
    r.u[2] = __builtin_amdgcn_perm(fbits(b[1]), fbits(b[0]), 0x07060302u);
    r.u[3] = __builtin_amdgcn_perm(fbits(b[3]), fbits(b[2]), 0x07060302u);
    return r.s;
}

__device__ __forceinline__ void gload_lds16(const void* src, void* ldsDst) {
    // 16B/lane async global->LDS; LDS dest = wave-uniform base + lane*16
    __builtin_amdgcn_global_load_lds((const GLB_AS void*)src, (LDS_AS void*)ldsDst, 16, 0, 0);
}

// ---------------------------------------------------------------------------
// Transpose fp32 [rows][cols] -> bf16 [cols][rows]  (weights to B^T=[N][K])
// ---------------------------------------------------------------------------
__global__ __launch_bounds__(256) void transpose_f32_bf16(
    const float* __restrict__ in, unsigned short* __restrict__ out,
    int rows, int cols)
{
    __shared__ float tile[32][33];
    const int c0 = blockIdx.x << 5, r0 = blockIdx.y << 5;
    const int tx = threadIdx.x, ty = threadIdx.y;
#pragma unroll
    for (int rr = ty; rr < 32; rr += 8)
        tile[rr][tx] = in[(size_t)(r0 + rr) * cols + (c0 + tx)];
    __syncthreads();
#pragma unroll
    for (int rr = ty; rr < 32; rr += 8)
        out[(size_t)(c0 + rr) * rows + (r0 + tx)] = f2b(tile[tx][rr]);
}

__global__ void zero_logits(float* __restrict__ logits) {
    logits[threadIdx.x] = 0.0f;   // 64 floats
}

// ---------------------------------------------------------------------------
// gather_h: h[m][k] = bf16(embed[x[m]][k]), m in [0,65536), k in [0,1024).
// Thread handles 8 consecutive k (32B read, 16B write). Pure streaming.
// ---------------------------------------------------------------------------
__global__ __launch_bounds__(256) void gather_h(
    const int* __restrict__ x, const float* __restrict__ embed,
    unsigned short* __restrict__ h)
{
    const size_t f = ((size_t)blockIdx.x * 256 + threadIdx.x) * 8;  // elem idx
    const int m = (int)(f >> 10);
    const int k = (int)(f & 1023);
    const float* src = embed + (size_t)x[m] * 1024 + k;
    f32x4 a = *(const f32x4*)(src);
    f32x4 b = *(const f32x4*)(src + 4);
    union { unsigned short us[8]; short8 s; } o;
#pragma unroll
    for (int i = 0; i < 4; ++i) o.us[i] = f2b(a[i]);
#pragma unroll
    for (int i = 0; i < 4; ++i) o.us[4 + i] = f2b(b[i]);
    *(short8*)(h + f) = o.s;
}

// ---------------------------------------------------------------------------
// GEMM1 (dense): qkv[m][n] = sum_k h[m][k] * WT[n][k]  (M=65536,N=3072,K=1024)
// Both operands bf16 via global_load_lds, XOR-swizzled slots (same layout as
// gemm_out_logits, proven). 4 waves (2x2 of 64x64), mfma 16x16x32.
// ---------------------------------------------------------------------------
__global__ __launch_bounds__(256) void gemm_qkv_dense(
    const unsigned short* __restrict__ h, const unsigned short* __restrict__ WT,
    unsigned short* __restrict__ qkv)
{
    __shared__ __align__(16) unsigned short As[4096];   // 8KB
    __shared__ __align__(16) unsigned short Bs[4096];   // 8KB

    const int tid = threadIdx.x;
    const int lane = tid & 63;
    const int wv = tid >> 6;
    const int wm = wv >> 1, wn = wv & 1;
    const int m0 = blockIdx.y << 7;
    const int n0 = blockIdx.x << 7;
    const int r = lane & 15, q4 = lane >> 4;

    const unsigned short* baseA[2];
    const unsigned short* baseB[2];
#pragma unroll
    for (int t = 0; t < 2; ++t) {
        int slot = wv * 128 + t * 64 + lane;      // [0,512): row=slot>>2, s=slot&3
        int row = slot >> 2;
        int g = (slot & 3) ^ ((row >> 1) & 3);    // source k-chunk (8 bf16)
        baseA[t] = h + (((size_t)(m0 + row)) << 10) + g * 8;
        baseB[t] = WT + (((size_t)(n0 + row)) << 10) + g * 8;
    }

    f32x4 acc[4][4];
#pragma unroll
    for (int i = 0; i < 4; ++i)
#pragma unroll
        for (int j = 0; j < 4; ++j) acc[i][j] = (f32x4){0.f, 0.f, 0.f, 0.f};

    for (int kt = 0; kt < 1024; kt += 32) {
        __syncthreads();
#pragma unroll
        for (int t = 0; t < 2; ++t) {
            gload_lds16(baseA[t] + kt, As + (size_t)(wv * 128 + t * 64) * 8);
            gload_lds16(baseB[t] + kt, Bs + (size_t)(wv * 128 + t * 64) * 8);
        }
        __syncthreads();

        short8 af[4], bfr[4];
#pragma unroll
        for (int i = 0; i < 4; ++i) {
            int lrow = wm * 64 + i * 16 + r;
            int slot = lrow * 4 + (q4 ^ ((lrow >> 1) & 3));
            af[i] = *(const short8*)(As + (size_t)slot * 8);
        }
#pragma unroll
        for (int j = 0; j < 4; ++j) {
            int lrow = wn * 64 + j * 16 + r;
            int slot = lrow * 4 + (q4 ^ ((lrow >> 1) & 3));
            bfr[j] = *(const short8*)(Bs + (size_t)slot * 8);
        }
#pragma unroll
        for (int i = 0; i < 4; ++i)
#pragma unroll
            for (int j = 0; j < 4; ++j)
                acc[i][j] = __builtin_amdgcn_mfma_f32_16x16x32_bf16(af[i], bfr[j], acc[i][j], 0, 0, 0);
    }

    // epilogue: C/D layout col=lane&15, row=q4*4+reg (m89-verified)
#pragma unroll
    for (int i = 0; i < 4; ++i) {
        int lmb = wm * 64 + i * 16 + q4 * 4;
#pragma unroll
        for (int j = 0; j < 4; ++j) {
            int ln = n0 + wn * 64 + j * 16 + r;
#pragma unroll
            for (int rg = 0; rg < 4; ++rg) {
                int m = m0 + lmb + rg;
                qkv[(size_t)m * 3072 + ln] = f2b(acc[i][j][rg]);
            }
        }
    }
}

// ---------------------------------------------------------------------------
// GEMM1 (fallback, R3-proven): fused fp32 gather, used if ws too small for h.
// ---------------------------------------------------------------------------
__global__ __launch_bounds__(256) void gemm_qkv_gather(
    const int* __restrict__ x, const float* __restrict__ embed,
    const unsigned short* __restrict__ WT, unsigned short* __restrict__ qkv)
{
    __shared__ __align__(16) float Asf[4096];           // 128 rows * 8 chunks * 4 floats (16KB)
    __shared__ __align__(16) unsigned short Bs[4096];   // 128 rows * 4 chunks * 8 bf16 (8KB)
    __shared__ int xs[128];

    const int tid = threadIdx.x;
    const int lane = tid & 63;
    const int wv = tid >> 6;
    const int wm = wv >> 1, wn = wv & 1;
    const int m0 = blockIdx.y << 7;
    const int n0 = blockIdx.x << 7;
    const int r = lane & 15, q4 = lane >> 4;

    if (tid < 128) xs[tid] = x[m0 + tid];
    __syncthreads();

    const float* baseA[4];
#pragma unroll
    for (int u = 0; u < 4; ++u) {
        int slot = wv * 256 + u * 64 + lane;      // [0,1024): row=slot>>3, s=slot&7
        int row = slot >> 3;
        int c = (slot & 7) ^ (row & 7);           // source k-chunk (4 floats)
        baseA[u] = embed + (size_t)xs[row] * 1024 + c * 4;
    }
    const unsigned short* baseB[2];
#pragma unroll
    for (int t = 0; t < 2; ++t) {
        int slot = wv * 128 + t * 64 + lane;      // [0,512): row=slot>>2, s=slot&3
        int row = slot >> 2;
        int g = (slot & 3) ^ ((row >> 1) & 3);    // source k-chunk (8 bf16)
        baseB[t] = WT + (((size_t)(n0 + row)) << 10) + g * 8;
    }

    f32x4 acc[4][4];
#pragma unroll
    for (int i = 0; i < 4; ++i)
#pragma unroll
        for (int j = 0; j < 4; ++j) acc[i][j] = (f32x4){0.f, 0.f, 0.f, 0.f};

    for (int kt = 0; kt < 1024; kt += 32) {
        __syncthreads();
#pragma unroll
        for (int u = 0; u < 4; ++u)
            gload_lds16(baseA[u] + kt, Asf + (size_t)(wv * 256 + u * 64) * 4);
#pragma unroll
        for (int t = 0; t < 2; ++t)
            gload_lds16(baseB[t] + kt, Bs + (size_t)(wv * 128 + t * 64) * 8);
        __syncthreads();

        short8 af[4], bfr[4];
#pragma unroll
        for (int i = 0; i < 4; ++i) {
            int lrow = wm * 64 + i * 16 + r;
            int sw = lrow & 7;
            f32x4 fa0 = *(const f32x4*)(Asf + (size_t)(lrow * 8 + ((2 * q4) ^ sw)) * 4);
            f32x4 fa1 = *(const f32x4*)(Asf + (size_t)(lrow * 8 + ((2 * q4 + 1) ^ sw)) * 4);
            af[i] = pack_bf16_rtz(fa0, fa1);
        }
#pragma unroll
        for (int j = 0; j < 4; ++j) {
            int lrow = wn * 64 + j * 16 + r;
            int slot = lrow * 4 + (q4 ^ ((lrow >> 1) & 3));
            bfr[j] = *(const short8*)(Bs + (size_t)slot * 8);
        }
#pragma unroll
        for (int i = 0; i < 4; ++i)
#pragma unroll
            for (int j = 0; j < 4; ++j)
                acc[i][j] = __builtin_amdgcn_mfma_f32_16x16x32_bf16(af[i], bfr[j], acc[i][j], 0, 0, 0);
    }

#pragma unroll
    for (int i = 0; i < 4; ++i) {
        int lmb = wm * 64 + i * 16 + q4 * 4;
#pragma unroll
        for (int j = 0; j < 4; ++j) {
            int ln = n0 + wn * 64 + j * 16 + r;
#pragma unroll
            for (int rg = 0; rg < 4; ++rg) {
                int m = m0 + lmb + rg;
                qkv[(size_t)m * 3072 + ln] = f2b(acc[i][j][rg]);
            }
        }
    }
}

// ---------------------------------------------------------------------------
// Attention over the batch dim. 1 wave per (l, head). qkv rows m=b*2048+l,
// cols: q=[0,1024) k=[1024,2048) v=[2048,3072), head slab nh*64+d.
// ---------------------------------------------------------------------------
__global__ __launch_bounds__(256) void attn(unsigned short* __restrict__ qkv)
{
    __shared__ __align__(16) unsigned short Vt[4][64 * 40]; // per-wave V^T [d][j], pad 40
    __shared__ __align__(16) unsigned short Ps[4][32 * 40]; // per-wave P [i][j], pad 40
    const int tid = threadIdx.x, lane = tid & 63, wv = tid >> 6;
    const int flat = (blockIdx.x << 2) + wv;     // 0..32767
    const int l = flat >> 4, nh = flat & 15;
    const int r = lane & 15, q4 = lane >> 4;
    const size_t ROWB = (size_t)2048 * 3072;     // batch stride in elements

    unsigned short* vt = Vt[wv];
    unsigned short* ps = Ps[wv];

    unsigned short* qb = qkv + (size_t)l * 3072 + nh * 64;
    const unsigned short* kb = qb + 1024;
    const unsigned short* vb = qb + 2048;

#pragma unroll
    for (int p = 0; p < 16; ++p) {
        unsigned short v0 = vb[(size_t)(2 * p) * ROWB + lane];
        unsigned short v1 = vb[(size_t)(2 * p + 1) * ROWB + lane];
        *(unsigned int*)(vt + lane * 40 + 2 * p) = (unsigned int)v0 | ((unsigned int)v1 << 16);
    }

    short8 aQ[2][2], bK[2][2];
#pragma unroll
    for (int it = 0; it < 2; ++it)
#pragma unroll
        for (int ks = 0; ks < 2; ++ks) {
            aQ[it][ks] = *(const short8*)(qb + (size_t)(it * 16 + r) * ROWB + ks * 32 + q4 * 8);
            bK[it][ks] = *(const short8*)(kb + (size_t)(it * 16 + r) * ROWB + ks * 32 + q4 * 8);
        }

    f32x4 S[2][2];
#pragma unroll
    for (int it = 0; it < 2; ++it)
#pragma unroll
        for (int jt = 0; jt < 2; ++jt) {
            f32x4 z = (f32x4){0.f, 0.f, 0.f, 0.f};
            z = __builtin_amdgcn_mfma_f32_16x16x32_bf16(aQ[it][0], bK[jt][0], z, 0, 0, 0);
            z = __builtin_amdgcn_mfma_f32_16x16x32_bf16(aQ[it][1], bK[jt][1], z, 0, 0, 0);
            S[it][jt] = z;
        }

#pragma unroll
    for (int it = 0; it < 2; ++it)
#pragma unroll
        for (int rg = 0; rg < 4; ++rg) {
            float s0 = S[it][0][rg] * 0.125f;
            float s1 = S[it][1][rg] * 0.125f;
            float mx = fmaxf(s0, s1);
#pragma unroll
            for (int d = 1; d < 16; d <<= 1) mx = fmaxf(mx, __shfl_xor(mx, d, 64));
            float e0 = __expf(s0 - mx), e1 = __expf(s1 - mx);
            float sm = e0 + e1;
#pragma unroll
            for (int d = 1; d < 16; d <<= 1) sm += __shfl_xor(sm, d, 64);
            float inv = 1.0f / sm;
            int i = it * 16 + q4 * 4 + rg;
            ps[i * 40 + r]      = f2b(e0 * inv);
            ps[i * 40 + 16 + r] = f2b(e1 * inv);
        }

    __asm__ volatile("s_waitcnt lgkmcnt(0)" ::: "memory");  // Vt + Ps visible (same wave)

    short8 aP[2], bV[4];
#pragma unroll
    for (int it = 0; it < 2; ++it)
        aP[it] = *(const short8*)(ps + (it * 16 + r) * 40 + q4 * 8);
#pragma unroll
    for (int dt = 0; dt < 4; ++dt)
        bV[dt] = *(const short8*)(vt + (dt * 16 + r) * 40 + q4 * 8);

    f32x4 O[2][4];
#pragma unroll
    for (int it = 0; it < 2; ++it)
#pragma unroll
        for (int dt = 0; dt < 4; ++dt) {
            f32x4 z = (f32x4){0.f, 0.f, 0.f, 0.f};
            O[it][dt] = __builtin_amdgcn_mfma_f32_16x16x32_bf16(aP[it], bV[dt], z, 0, 0, 0);
        }

#pragma unroll
    for (int it = 0; it < 2; ++it)
#pragma unroll
        for (int dt = 0; dt < 4; ++dt)
#pragma unroll
            for (int rg = 0; rg < 4; ++rg) {
                int i = it * 16 + q4 * 4 + rg;
                qb[(size_t)i * ROWB + dt * 16 + r] = f2b(O[it][dt][rg]);
            }
}

// ---------------------------------------------------------------------------
// GEMM2: out[m][e] = h[m][e] + sum_k att[m][k]*WoT[e][k]; fused logits:
// logits[b][c] += sum_e out[m][e]*Wf[l*1024+e][c]. embed/Wf read as fp32.
// ---------------------------------------------------------------------------
__global__ __launch_bounds__(256) void gemm_out_logits(
    const int* __restrict__ x, const float* __restrict__ embed,
    const unsigned short* __restrict__ qkv, const unsigned short* __restrict__ WoT,
    const float* __restrict__ Wf, float* __restrict__ logits)
{
    __shared__ __align__(16) unsigned short As[4096];
    __shared__ __align__(16) unsigned short Bs[4096];
    __shared__ int xs[128];
    __shared__ float red[2];

    const int tid = threadIdx.x;
    const int lane = tid & 63;
    const int wv = tid >> 6;
    const int wm = wv >> 1, wn = wv & 1;
    const int m0 = blockIdx.y << 7;
    const int n0 = blockIdx.x << 7;
    const int r = lane & 15, q4 = lane >> 4;

    if (tid < 128) xs[tid] = x[m0 + tid];
    if (tid == 0) { red[0] = 0.f; red[1] = 0.f; }
    __syncthreads();

    const unsigned short* baseA[2];
    const unsigned short* baseB[2];
#pragma unroll
    for (int t = 0; t < 2; ++t) {
        int slot = wv * 128 + t * 64 + lane;
        int row = slot >> 2;
        int g = (slot & 3) ^ ((row >> 1) & 3);
        baseA[t] = qkv + (size_t)(m0 + row) * 3072 + g * 8;   // att in cols [0,1024)
        baseB[t] = WoT + (((size_t)(n0 + row)) << 10) + g * 8;
    }

    f32x4 acc[4][4];
#pragma unroll
    for (int i = 0; i < 4; ++i)
#pragma unroll
        for (int j = 0; j < 4; ++j) acc[i][j] = (f32x4){0.f, 0.f, 0.f, 0.f};

    for (int kt = 0; kt < 1024; kt += 32) {
        __syncthreads();
#pragma unroll
        for (int t = 0; t < 2; ++t) {
            gload_lds16(baseA[t] + kt, As + (size_t)(wv * 128 + t * 64) * 8);
            gload_lds16(baseB[t] + kt, Bs + (size_t)(wv * 128 + t * 64) * 8);
        }
        __syncthreads();

        short8 af[4], bfr[4];
#pragma unroll
        for (int i = 0; i < 4; ++i) {
            int lrow = wm * 64 + i * 16 + r;
            int slot = lrow * 4 + (q4 ^ ((lrow >> 1) & 3));
            af[i] = *(const short8*)(As + (size_t)slot * 8);
        }
#pragma unroll
        for (int j = 0; j < 4; ++j) {
            int lrow = wn * 64 + j * 16 + r;
            int slot = lrow * 4 + (q4 ^ ((lrow >> 1) & 3));
            bfr[j] = *(const short8*)(Bs + (size_t)slot * 8);
        }
#pragma unroll
        for (int i = 0; i < 4; ++i)
#pragma unroll
            for (int j = 0; j < 4; ++j)
                acc[i][j] = __builtin_amdgcn_mfma_f32_16x16x32_bf16(af[i], bfr[j], acc[i][j], 0, 0, 0);
    }

    // epilogue: residual (fp32 embed gather) + Wf (fp32) reduction
    float c0 = 0.f, c1 = 0.f;
#pragma unroll
    for (int i = 0; i < 4; ++i) {
        int lmb = wm * 64 + i * 16 + q4 * 4;
#pragma unroll
        for (int j = 0; j < 4; ++j) {
            int e = n0 + wn * 64 + j * 16 + r;
#pragma unroll
            for (int rg = 0; rg < 4; ++rg) {
                int lm = lmb + rg;
                int m = m0 + lm;
                int ll = m & 2047;
                float hv = embed[(size_t)xs[lm] * 1024 + e];
                float outv = acc[i][j][rg] + hv;
                const float* wfp = Wf + ((size_t)(ll << 10) + e) * 2;
                c0 += outv * wfp[0];
                c1 += outv * wfp[1];
            }
        }
    }
#pragma unroll
    for (int d = 1; d < 64; d <<= 1) {
        c0 += __shfl_xor(c0, d, 64);
        c1 += __shfl_xor(c1, d, 64);
    }
    __syncthreads();
    if (lane == 0) { atomicAdd(&red[0], c0); atomicAdd(&red[1], c1); }
    __syncthreads();
    if (tid == 0) {
        int b = m0 >> 11;
        atomicAdd(&logits[b * 2 + 0], red[0]);
        atomicAdd(&logits[b * 2 + 1], red[1]);
    }
}

// ---------------------------------------------------------------------------
// Loss: -mean_b( log_softmax(logits[b]+bf)[y_b] ), C=2. Output fp32 scalar.
// ---------------------------------------------------------------------------
__global__ void loss_k(const float* __restrict__ logits, const int* __restrict__ y,
                       const float* __restrict__ bfb, float* __restrict__ out)
{
    const int t = threadIdx.x;
    float contrib = 0.f;
    if (t < 32) {
        float l0 = logits[t * 2 + 0] + bfb[0];
        float l1 = logits[t * 2 + 1] + bfb[1];
        float mx = fmaxf(l0, l1);
        float lse = mx + logf(expf(l0 - mx) + expf(l1 - mx));
        float chosen = (y[t] == 0) ? l0 : l1;
        contrib = -(chosen - lse) * (1.0f / 32.0f);
    }
#pragma unroll
    for (int d = 1; d < 64; d <<= 1) contrib += __shfl_xor(contrib, d, 64);
    if (t == 0) *out = contrib;    // fp32 output
}

// ---------------------------------------------------------------------------
extern "C" void kernel_launch(void* const* d_in, const int* in_sizes, int n_in,
                              void* d_out, int out_size, void* d_ws, size_t ws_size,
                              hipStream_t stream) {
    const int* x      = (const int*)d_in[0];
    const int* y      = (const int*)d_in[1];
    const float* emb  = (const float*)d_in[2];
    const float* Wq   = (const float*)d_in[3];
    const float* Wkv  = (const float*)d_in[4];
    const float* Wo   = (const float*)d_in[5];
    const float* Wf   = (const float*)d_in[6];
    const float* bfb  = (const float*)d_in[7];

    char* ws = (char*)d_ws;
    unsigned short* qkv    = (unsigned short*)ws;                        // 384 MB bf16
    unsigned short* WqkvT  = (unsigned short*)(ws + 402653184);          // [3072][1024] bf16
    unsigned short* WoT    = (unsigned short*)(ws + 408944640);          // [1024][1024] bf16
    float*          logits = (float*)(ws + 411041792);                   // [32][2] fp32
    float*          out    = (float*)d_out;

    const size_t H_OFF  = 411045888ull;                                  // 4KB past logits
    const size_t H_SIZE = 134217728ull;                                  // [65536][1024] bf16
    const bool   have_h = (ws_size >= H_OFF + H_SIZE);

    zero_logits<<<1, 64, 0, stream>>>(logits);

    transpose_f32_bf16<<<dim3(32, 32), dim3(32, 8), 0, stream>>>(Wq, WqkvT, 1024, 1024);
    transpose_f32_bf16<<<dim3(64, 32), dim3(32, 8), 0, stream>>>(Wkv, WqkvT + 1024 * 1024, 1024, 2048);
    transpose_f32_bf16<<<dim3(32, 32), dim3(32, 8), 0, stream>>>(Wo, WoT, 1024, 1024);

    if (have_h) {
        unsigned short* h = (unsigned short*)(ws + H_OFF);
        gather_h<<<32768, 256, 0, stream>>>(x, emb, h);
        gemm_qkv_dense<<<dim3(24, 512), 256, 0, stream>>>(h, WqkvT, qkv);
    } else {
        gemm_qkv_gather<<<dim3(24, 512), 256, 0, stream>>>(x, emb, WqkvT, qkv);
    }

    attn<<<8192, 256, 0, stream>>>(qkv);
    gemm_out_logits<<<dim3(8, 512), 256, 0, stream>>>(x, emb, qkv, WoT, Wf, logits);
    loss_k<<<1, 64, 0, stream>>>(logits, y, bfb, out);
}

// Round 4
// 1310.500 us; speedup vs baseline: 1.2575x; 1.1337x over previous
//
#include <hip/hip_runtime.h>
#include <hip/hip_bf16.h>

// R7: replace gemm_out_logits (att@Wo GEMM + random fp32 embed gather + Wf
// epilogue; est 300-450us, latency-bound) with the algebraic refactor:
//   logits[b,c] = sum_{l,e} h[b,l,e] Wf[l*1024+e,c]
//               + sum_{l,k} att[b,l,k] G[l,k,c],
//   G[l,k,c] = sum_e Wo[k,e] Wf[l*1024+e,c]   (16MB fp32, one tiny GEMM).
// New kernels: cvt_f32_bf16 (Wo), wft_prep (Wf -> [l*2+c][e] bf16, staged in
// the not-yet-written qkv region), g_gemm (M=1024,N=4096,K=1024, proven
// structure, fp32 scatter epilogue into G), logits_fused (streaming: att+h
// rows vs L2-resident G/Wf slabs, per-l blocks so 32 batches share slabs),
// sliced-partial atomics + loss_k reduction. Old path kept as ws fallback.
// R6 carry: gather_h + gemm_qkv_dense (738 TF) + attn unchanged.

typedef __attribute__((ext_vector_type(8))) short short8;   // 8 x bf16
typedef __attribute__((ext_vector_type(4))) float f32x4;

#define GLB_AS __attribute__((address_space(1)))
#define LDS_AS __attribute__((address_space(3)))

__device__ __forceinline__ float b2f(unsigned short u) {
    union { unsigned int i; float f; } v; v.i = ((unsigned int)u) << 16; return v.f;
}
__device__ __forceinline__ unsigned short f2b(float f) {
    union { float f; unsigned int i; } v; v.f = f;
    unsigned int u = v.i;
    u += 0x7fffu + ((u >> 16) & 1u);   // RNE
    return (unsigned short)(u >> 16);
}
__device__ __forceinline__ unsigned int fbits(float f) {
    union { float f; unsigned int i; } v; v.f = f; return v.i;
}
// pack hi16(a0..a3,b0..b3) -> short8 bf16 (RTZ truncation), via v_perm_b32
__device__ __forceinline__ short8 pack_bf16_rtz(f32x4 a, f32x4 b) {
    union { unsigned int u[4]; short8 s; } r;
    r.u[0] = __builtin_amdgcn_perm(fbits(a[1]), fbits(a[0]), 0x07060302u);
    r.u[1] = __builtin_amdgcn_perm(fbits(a[3]), fbits(a[2]), 0x07060302u);
    r.u[2] = __builtin_amdgcn_perm(fbits(b[1]), fbits(b[0]), 0x07060302u);
    r.u[3] = __builtin_amdgcn_perm(fbits(b[3]), fbits(b[2]), 0x07060302u);
    return r.s;
}

__device__ __forceinline__ void gload_lds16(const void* src, void* ldsDst) {
    // 16B/lane async global->LDS; LDS dest = wave-uniform base + lane*16
    __builtin_amdgcn_global_load_lds((const GLB_AS void*)src, (LDS_AS void*)ldsDst, 16, 0, 0);
}

// ---------------------------------------------------------------------------
// Transpose fp32 [rows][cols] -> bf16 [cols][rows]  (weights to B^T=[N][K])
// ---------------------------------------------------------------------------
__global__ __launch_bounds__(256) void transpose_f32_bf16(
    const float* __restrict__ in, unsigned short* __restrict__ out,
    int rows, int cols)
{
    __shared__ float tile[32][33];
    const int c0 = blockIdx.x << 5, r0 = blockIdx.y << 5;
    const int tx = threadIdx.x, ty = threadIdx.y;
#pragma unroll
    for (int rr = ty; rr < 32; rr += 8)
        tile[rr][tx] = in[(size_t)(r0 + rr) * cols + (c0 + tx)];
    __syncthreads();
#pragma unroll
    for (int rr = ty; rr < 32; rr += 8)
        out[(size_t)(c0 + rr) * rows + (r0 + tx)] = f2b(tile[tx][rr]);
}

__global__ void zero_n(float* __restrict__ p, int n) {
    for (int i = threadIdx.x; i < n; i += 256) p[i] = 0.0f;
}

// ---------------------------------------------------------------------------
// cvt_f32_bf16: straight elementwise convert (8 elems/thread).
// ---------------------------------------------------------------------------
__global__ __launch_bounds__(256) void cvt_f32_bf16(
    const float* __restrict__ in, unsigned short* __restrict__ out)
{
    const size_t f = ((size_t)blockIdx.x * 256 + threadIdx.x) * 8;
    f32x4 a = *(const f32x4*)(in + f);
    f32x4 b = *(const f32x4*)(in + f + 4);
    union { unsigned short us[8]; short8 s; } o;
#pragma unroll
    for (int i = 0; i < 4; ++i) o.us[i] = f2b(a[i]);
#pragma unroll
    for (int i = 0; i < 4; ++i) o.us[4 + i] = f2b(b[i]);
    *(short8*)(out + f) = o.s;
}

// ---------------------------------------------------------------------------
// wft_prep: WfT[n][e] = bf16(Wf[(n>>1)*1024 + e][n&1]),  n=(l*2+c) in [0,4096).
// ---------------------------------------------------------------------------
__global__ __launch_bounds__(256) void wft_prep(
    const float* __restrict__ Wf, unsigned short* __restrict__ WfT)
{
    const size_t f = ((size_t)blockIdx.x * 256 + threadIdx.x) * 8;
    const int n = (int)(f >> 10);
    const int e0 = (int)(f & 1023);
    const int c = n & 1;
    const float* src = Wf + ((size_t)(n >> 1) * 1024 + e0) * 2;
    float vals[16];
#pragma unroll
    for (int q = 0; q < 4; ++q) {
        f32x4 v = *(const f32x4*)(src + q * 4);
        vals[q * 4 + 0] = v[0]; vals[q * 4 + 1] = v[1];
        vals[q * 4 + 2] = v[2]; vals[q * 4 + 3] = v[3];
    }
    union { unsigned short us[8]; short8 s; } o;
#pragma unroll
    for (int i = 0; i < 8; ++i) o.us[i] = f2b(vals[2 * i + c]);
    *(short8*)(WfT + f) = o.s;
}

// ---------------------------------------------------------------------------
// gather_h: h[m][k] = bf16(embed[x[m]][k]), m in [0,65536), k in [0,1024).
// ---------------------------------------------------------------------------
__global__ __launch_bounds__(256) void gather_h(
    const int* __restrict__ x, const float* __restrict__ embed,
    unsigned short* __restrict__ h)
{
    const size_t f = ((size_t)blockIdx.x * 256 + threadIdx.x) * 8;  // elem idx
    const int m = (int)(f >> 10);
    const int k = (int)(f & 1023);
    const float* src = embed + (size_t)x[m] * 1024 + k;
    f32x4 a = *(const f32x4*)(src);
    f32x4 b = *(const f32x4*)(src + 4);
    union { unsigned short us[8]; short8 s; } o;
#pragma unroll
    for (int i = 0; i < 4; ++i) o.us[i] = f2b(a[i]);
#pragma unroll
    for (int i = 0; i < 4; ++i) o.us[4 + i] = f2b(b[i]);
    *(short8*)(h + f) = o.s;
}

// ---------------------------------------------------------------------------
// GEMM1 (dense): qkv[m][n] = sum_k h[m][k] * WT[n][k]  (M=65536,N=3072,K=1024)
// ---------------------------------------------------------------------------
__global__ __launch_bounds__(256) void gemm_qkv_dense(
    const unsigned short* __restrict__ h, const unsigned short* __restrict__ WT,
    unsigned short* __restrict__ qkv)
{
    __shared__ __align__(16) unsigned short As[4096];   // 8KB
    __shared__ __align__(16) unsigned short Bs[4096];   // 8KB

    const int tid = threadIdx.x;
    const int lane = tid & 63;
    const int wv = tid >> 6;
    const int wm = wv >> 1, wn = wv & 1;
    const int m0 = blockIdx.y << 7;
    const int n0 = blockIdx.x << 7;
    const int r = lane & 15, q4 = lane >> 4;

    const unsigned short* baseA[2];
    const unsigned short* baseB[2];
#pragma unroll
    for (int t = 0; t < 2; ++t) {
        int slot = wv * 128 + t * 64 + lane;      // [0,512): row=slot>>2, s=slot&3
        int row = slot >> 2;
        int g = (slot & 3) ^ ((row >> 1) & 3);    // source k-chunk (8 bf16)
        baseA[t] = h + (((size_t)(m0 + row)) << 10) + g * 8;
        baseB[t] = WT + (((size_t)(n0 + row)) << 10) + g * 8;
    }

    f32x4 acc[4][4];
#pragma unroll
    for (int i = 0; i < 4; ++i)
#pragma unroll
        for (int j = 0; j < 4; ++j) acc[i][j] = (f32x4){0.f, 0.f, 0.f, 0.f};

    for (int kt = 0; kt < 1024; kt += 32) {
        __syncthreads();
#pragma unroll
        for (int t = 0; t < 2; ++t) {
            gload_lds16(baseA[t] + kt, As + (size_t)(wv * 128 + t * 64) * 8);
            gload_lds16(baseB[t] + kt, Bs + (size_t)(wv * 128 + t * 64) * 8);
        }
        __syncthreads();

        short8 af[4], bfr[4];
#pragma unroll
        for (int i = 0; i < 4; ++i) {
            int lrow = wm * 64 + i * 16 + r;
            int slot = lrow * 4 + (q4 ^ ((lrow >> 1) & 3));
            af[i] = *(const short8*)(As + (size_t)slot * 8);
        }
#pragma unroll
        for (int j = 0; j < 4; ++j) {
            int lrow = wn * 64 + j * 16 + r;
            int slot = lrow * 4 + (q4 ^ ((lrow >> 1) & 3));
            bfr[j] = *(const short8*)(Bs + (size_t)slot * 8);
        }
#pragma unroll
        for (int i = 0; i < 4; ++i)
#pragma unroll
            for (int j = 0; j < 4; ++j)
                acc[i][j] = __builtin_amdgcn_mfma_f32_16x16x32_bf16(af[i], bfr[j], acc[i][j], 0, 0, 0);
    }

    // epilogue: C/D layout col=lane&15, row=q4*4+reg (m89-verified)
#pragma unroll
    for (int i = 0; i < 4; ++i) {
        int lmb = wm * 64 + i * 16 + q4 * 4;
#pragma unroll
        for (int j = 0; j < 4; ++j) {
            int ln = n0 + wn * 64 + j * 16 + r;
#pragma unroll
            for (int rg = 0; rg < 4; ++rg) {
                int m = m0 + lmb + rg;
                qkv[(size_t)m * 3072 + ln] = f2b(acc[i][j][rg]);
            }
        }
    }
}

// ---------------------------------------------------------------------------
// g_gemm: C[k][n] = sum_e Wob[k][e] * WfT[n][e]  (M=1024, N=4096, K=1024),
// scatter epilogue into G[l][k][c] fp32 with l=n>>1, c=n&1.
// ---------------------------------------------------------------------------
__global__ __launch_bounds__(256) void g_gemm(
    const unsigned short* __restrict__ A, const unsigned short* __restrict__ BT,
    float* __restrict__ G)
{
    __shared__ __align__(16) unsigned short As[4096];
    __shared__ __align__(16) unsigned short Bs[4096];

    const int tid = threadIdx.x;
    const int lane = tid & 63;
    const int wv = tid >> 6;
    const int wm = wv >> 1, wn = wv & 1;
    const int m0 = blockIdx.y << 7;
    const int n0 = blockIdx.x << 7;
    const int r = lane & 15, q4 = lane >> 4;

    const unsigned short* baseA[2];
    const unsigned short* baseB[2];
#pragma unroll
    for (int t = 0; t < 2; ++t) {
        int slot = wv * 128 + t * 64 + lane;
        int row = slot >> 2;
        int g = (slot & 3) ^ ((row >> 1) & 3);
        baseA[t] = A + (((size_t)(m0 + row)) << 10) + g * 8;
        baseB[t] = BT + (((size_t)(n0 + row)) << 10) + g * 8;
    }

    f32x4 acc[4][4];
#pragma unroll
    for (int i = 0; i < 4; ++i)
#pragma unroll
        for (int j = 0; j < 4; ++j) acc[i][j] = (f32x4){0.f, 0.f, 0.f, 0.f};

    for (int kt = 0; kt < 1024; kt += 32) {
        __syncthreads();
#pragma unroll
        for (int t = 0; t < 2; ++t) {
            gload_lds16(baseA[t] + kt, As + (size_t)(wv * 128 + t * 64) * 8);
            gload_lds16(baseB[t] + kt, Bs + (size_t)(wv * 128 + t * 64) * 8);
        }
        __syncthreads();

        short8 af[4], bfr[4];
#pragma unroll
        for (int i = 0; i < 4; ++i) {
            int lrow = wm * 64 + i * 16 + r;
            int slot = lrow * 4 + (q4 ^ ((lrow >> 1) & 3));
            af[i] = *(const short8*)(As + (size_t)slot * 8);
        }
#pragma unroll
        for (int j = 0; j < 4; ++j) {
            int lrow = wn * 64 + j * 16 + r;
            int slot = lrow * 4 + (q4 ^ ((lrow >> 1) & 3));
            bfr[j] = *(const short8*)(Bs + (size_t)slot * 8);
        }
#pragma unroll
        for (int i = 0; i < 4; ++i)
#pragma unroll
            for (int j = 0; j < 4; ++j)
                acc[i][j] = __builtin_amdgcn_mfma_f32_16x16x32_bf16(af[i], bfr[j], acc[i][j], 0, 0, 0);
    }

#pragma unroll
    for (int i = 0; i < 4; ++i) {
        int lmb = wm * 64 + i * 16 + q4 * 4;
#pragma unroll
        for (int j = 0; j < 4; ++j) {
            int n = n0 + wn * 64 + j * 16 + r;
#pragma unroll
            for (int rg = 0; rg < 4; ++rg) {
                int k = m0 + lmb + rg;
                G[(size_t)(n >> 1) * 2048 + k * 2 + (n & 1)] = acc[i][j][rg];
            }
        }
    }
}

// ---------------------------------------------------------------------------
// GEMM1 (fallback, R3-proven): fused fp32 gather, used if ws too small for h.
// ---------------------------------------------------------------------------
__global__ __launch_bounds__(256) void gemm_qkv_gather(
    const int* __restrict__ x, const float* __restrict__ embed,
    const unsigned short* __restrict__ WT, unsigned short* __restrict__ qkv)
{
    __shared__ __align__(16) float Asf[4096];
    __shared__ __align__(16) unsigned short Bs[4096];
    __shared__ int xs[128];

    const int tid = threadIdx.x;
    const int lane = tid & 63;
    const int wv = tid >> 6;
    const int wm = wv >> 1, wn = wv & 1;
    const int m0 = blockIdx.y << 7;
    const int n0 = blockIdx.x << 7;
    const int r = lane & 15, q4 = lane >> 4;

    if (tid < 128) xs[tid] = x[m0 + tid];
    __syncthreads();

    const float* baseA[4];
#pragma unroll
    for (int u = 0; u < 4; ++u) {
        int slot = wv * 256 + u * 64 + lane;
        int row = slot >> 3;
        int c = (slot & 7) ^ (row & 7);
        baseA[u] = embed + (size_t)xs[row] * 1024 + c * 4;
    }
    const unsigned short* baseB[2];
#pragma unroll
    for (int t = 0; t < 2; ++t) {
        int slot = wv * 128 + t * 64 + lane;
        int row = slot >> 2;
        int g = (slot & 3) ^ ((row >> 1) & 3);
        baseB[t] = WT + (((size_t)(n0 + row)) << 10) + g * 8;
    }

    f32x4 acc[4][4];
#pragma unroll
    for (int i = 0; i < 4; ++i)
#pragma unroll
        for (int j = 0; j < 4; ++j) acc[i][j] = (f32x4){0.f, 0.f, 0.f, 0.f};

    for (int kt = 0; kt < 1024; kt += 32) {
        __syncthreads();
#pragma unroll
        for (int u = 0; u < 4; ++u)
            gload_lds16(baseA[u] + kt, Asf + (size_t)(wv * 256 + u * 64) * 4);
#pragma unroll
        for (int t = 0; t < 2; ++t)
            gload_lds16(baseB[t] + kt, Bs + (size_t)(wv * 128 + t * 64) * 8);
        __syncthreads();

        short8 af[4], bfr[4];
#pragma unroll
        for (int i = 0; i < 4; ++i) {
            int lrow = wm * 64 + i * 16 + r;
            int sw = lrow & 7;
            f32x4 fa0 = *(const f32x4*)(Asf + (size_t)(lrow * 8 + ((2 * q4) ^ sw)) * 4);
            f32x4 fa1 = *(const f32x4*)(Asf + (size_t)(lrow * 8 + ((2 * q4 + 1) ^ sw)) * 4);
            af[i] = pack_bf16_rtz(fa0, fa1);
        }
#pragma unroll
        for (int j = 0; j < 4; ++j) {
            int lrow = wn * 64 + j * 16 + r;
            int slot = lrow * 4 + (q4 ^ ((lrow >> 1) & 3));
            bfr[j] = *(const short8*)(Bs + (size_t)slot * 8);
        }
#pragma unroll
        for (int i = 0; i < 4; ++i)
#pragma unroll
            for (int j = 0; j < 4; ++j)
                acc[i][j] = __builtin_amdgcn_mfma_f32_16x16x32_bf16(af[i], bfr[j], acc[i][j], 0, 0, 0);
    }

#pragma unroll
    for (int i = 0; i < 4; ++i) {
        int lmb = wm * 64 + i * 16 + q4 * 4;
#pragma unroll
        for (int j = 0; j < 4; ++j) {
            int ln = n0 + wn * 64 + j * 16 + r;
#pragma unroll
            for (int rg = 0; rg < 4; ++rg) {
                int m = m0 + lmb + rg;
                qkv[(size_t)m * 3072 + ln] = f2b(acc[i][j][rg]);
            }
        }
    }
}

// ---------------------------------------------------------------------------
// Attention over the batch dim. 1 wave per (l, head). Unchanged from R6.
// ---------------------------------------------------------------------------
__global__ __launch_bounds__(256) void attn(unsigned short* __restrict__ qkv)
{
    __shared__ __align__(16) unsigned short Vt[4][64 * 40];
    __shared__ __align__(16) unsigned short Ps[4][32 * 40];
    const int tid = threadIdx.x, lane = tid & 63, wv = tid >> 6;
    const int flat = (blockIdx.x << 2) + wv;
    const int l = flat >> 4, nh = flat & 15;
    const int r = lane & 15, q4 = lane >> 4;
    const size_t ROWB = (size_t)2048 * 3072;

    unsigned short* vt = Vt[wv];
    unsigned short* ps = Ps[wv];

    unsigned short* qb = qkv + (size_t)l * 3072 + nh * 64;
    const unsigned short* kb = qb + 1024;
    const unsigned short* vb = qb + 2048;

#pragma unroll
    for (int p = 0; p < 16; ++p) {
        unsigned short v0 = vb[(size_t)(2 * p) * ROWB + lane];
        unsigned short v1 = vb[(size_t)(2 * p + 1) * ROWB + lane];
        *(unsigned int*)(vt + lane * 40 + 2 * p) = (unsigned int)v0 | ((unsigned int)v1 << 16);
    }

    short8 aQ[2][2], bK[2][2];
#pragma unroll
    for (int it = 0; it < 2; ++it)
#pragma unroll
        for (int ks = 0; ks < 2; ++ks) {
            aQ[it][ks] = *(const short8*)(qb + (size_t)(it * 16 + r) * ROWB + ks * 32 + q4 * 8);
            bK[it][ks] = *(const short8*)(kb + (size_t)(it * 16 + r) * ROWB + ks * 32 + q4 * 8);
        }

    f32x4 S[2][2];
#pragma unroll
    for (int it = 0; it < 2; ++it)
#pragma unroll
        for (int jt = 0; jt < 2; ++jt) {
            f32x4 z = (f32x4){0.f, 0.f, 0.f, 0.f};
            z = __builtin_amdgcn_mfma_f32_16x16x32_bf16(aQ[it][0], bK[jt][0], z, 0, 0, 0);
            z = __builtin_amdgcn_mfma_f32_16x16x32_bf16(aQ[it][1], bK[jt][1], z, 0, 0, 0);
            S[it][jt] = z;
        }

#pragma unroll
    for (int it = 0; it < 2; ++it)
#pragma unroll
        for (int rg = 0; rg < 4; ++rg) {
            float s0 = S[it][0][rg] * 0.125f;
            float s1 = S[it][1][rg] * 0.125f;
            float mx = fmaxf(s0, s1);
#pragma unroll
            for (int d = 1; d < 16; d <<= 1) mx = fmaxf(mx, __shfl_xor(mx, d, 64));
            float e0 = __expf(s0 - mx), e1 = __expf(s1 - mx);
            float sm = e0 + e1;
#pragma unroll
            for (int d = 1; d < 16; d <<= 1) sm += __shfl_xor(sm, d, 64);
            float inv = 1.0f / sm;
            int i = it * 16 + q4 * 4 + rg;
            ps[i * 40 + r]      = f2b(e0 * inv);
            ps[i * 40 + 16 + r] = f2b(e1 * inv);
        }

    __asm__ volatile("s_waitcnt lgkmcnt(0)" ::: "memory");

    short8 aP[2], bV[4];
#pragma unroll
    for (int it = 0; it < 2; ++it)
        aP[it] = *(const short8*)(ps + (it * 16 + r) * 40 + q4 * 8);
#pragma unroll
    for (int dt = 0; dt < 4; ++dt)
        bV[dt] = *(const short8*)(vt + (dt * 16 + r) * 40 + q4 * 8);

    f32x4 O[2][4];
#pragma unroll
    for (int it = 0; it < 2; ++it)
#pragma unroll
        for (int dt = 0; dt < 4; ++dt) {
            f32x4 z = (f32x4){0.f, 0.f, 0.f, 0.f};
            O[it][dt] = __builtin_amdgcn_mfma_f32_16x16x32_bf16(aP[it], bV[dt], z, 0, 0, 0);
        }

#pragma unroll
    for (int it = 0; it < 2; ++it)
#pragma unroll
        for (int dt = 0; dt < 4; ++dt)
#pragma unroll
            for (int rg = 0; rg < 4; ++rg) {
                int i = it * 16 + q4 * 4 + rg;
                qb[(size_t)i * ROWB + dt * 16 + r] = f2b(O[it][dt][rg]);
            }
}

// ---------------------------------------------------------------------------
// logits_fused: block = one l (2048 blocks). partial[(l&31)][b*2+c] +=
//   sum_k att[b*2048+l][k]*G[l][k][c] + sum_e h[b*2048+l][e]*Wf[l*1024+e][c].
// 4 waves x 8 batches each; G/Wf slabs (16KB) L1/L2-shared across 32 batches.
// ---------------------------------------------------------------------------
__global__ __launch_bounds__(256) void logits_fused(
    const unsigned short* __restrict__ qkv, const unsigned short* __restrict__ h,
    const float* __restrict__ G, const float* __restrict__ Wf,
    float* __restrict__ partial)
{
    const int tid = threadIdx.x, lane = tid & 63, wv = tid >> 6;
    const int l = blockIdx.x;                   // 0..2047
    const float* Gl  = G  + (size_t)l * 2048;   // [k][c] fp32
    const float* Wfl = Wf + (size_t)l * 2048;   // [e][c] fp32 (contiguous slab)

    for (int bi = 0; bi < 8; ++bi) {
        const int b = wv * 8 + bi;
        const size_t m = (size_t)b * 2048 + l;
        const unsigned short* arow = qkv + m * 3072;   // att in cols [0,1024)
        const unsigned short* hrow = h + (m << 10);
        union { short8 s[2]; unsigned short us[16]; } av, hv;
        av.s[0] = *(const short8*)(arow + lane * 16);
        av.s[1] = *(const short8*)(arow + lane * 16 + 8);
        hv.s[0] = *(const short8*)(hrow + lane * 16);
        hv.s[1] = *(const short8*)(hrow + lane * 16 + 8);
        float c0 = 0.f, c1 = 0.f;
#pragma unroll
        for (int j = 0; j < 8; ++j) {
            f32x4 g = *(const f32x4*)(Gl  + lane * 32 + j * 4);   // k=lane*16+2j, both c
            f32x4 w = *(const f32x4*)(Wfl + lane * 32 + j * 4);
            float a0 = b2f(av.us[2 * j]),     a1 = b2f(av.us[2 * j + 1]);
            float h0 = b2f(hv.us[2 * j]),     h1 = b2f(hv.us[2 * j + 1]);
            c0 += a0 * g[0] + a1 * g[2] + h0 * w[0] + h1 * w[2];
            c1 += a0 * g[1] + a1 * g[3] + h0 * w[1] + h1 * w[3];
        }
#pragma unroll
        for (int d = 1; d < 64; d <<= 1) {
            c0 += __shfl_xor(c0, d, 64);
            c1 += __shfl_xor(c1, d, 64);
        }
        if (lane == 0) {
            atomicAdd(&partial[(l & 31) * 64 + b * 2 + 0], c0);
            atomicAdd(&partial[(l & 31) * 64 + b * 2 + 1], c1);
        }
    }
}

// ---------------------------------------------------------------------------
// GEMM2 fallback (old path): out = h + att@WoT, fused Wf reduction.
// ---------------------------------------------------------------------------
__global__ __launch_bounds__(256) void gemm_out_logits(
    const int* __restrict__ x, const float* __restrict__ embed,
    const unsigned short* __restrict__ qkv, const unsigned short* __restrict__ WoT,
    const float* __restrict__ Wf, float* __restrict__ logits)
{
    __shared__ __align__(16) unsigned short As[4096];
    __shared__ __align__(16) unsigned short Bs[4096];
    __shared__ int xs[128];
    __shared__ float red[2];

    const int tid = threadIdx.x;
    const int lane = tid & 63;
    const int wv = tid >> 6;
    const int wm = wv >> 1, wn = wv & 1;
    const int m0 = blockIdx.y << 7;
    const int n0 = blockIdx.x << 7;
    const int r = lane & 15, q4 = lane >> 4;

    if (tid < 128) xs[tid] = x[m0 + tid];
    if (tid == 0) { red[0] = 0.f; red[1] = 0.f; }
    __syncthreads();

    const unsigned short* baseA[2];
    const unsigned short* baseB[2];
#pragma unroll
    for (int t = 0; t < 2; ++t) {
        int slot = wv * 128 + t * 64 + lane;
        int row = slot >> 2;
        int g = (slot & 3) ^ ((row >> 1) & 3);
        baseA[t] = qkv + (size_t)(m0 + row) * 3072 + g * 8;
        baseB[t] = WoT + (((size_t)(n0 + row)) << 10) + g * 8;
    }

    f32x4 acc[4][4];
#pragma unroll
    for (int i = 0; i < 4; ++i)
#pragma unroll
        for (int j = 0; j < 4; ++j) acc[i][j] = (f32x4){0.f, 0.f, 0.f, 0.f};

    for (int kt = 0; kt < 1024; kt += 32) {
        __syncthreads();
#pragma unroll
        for (int t = 0; t < 2; ++t) {
            gload_lds16(baseA[t] + kt, As + (size_t)(wv * 128 + t * 64) * 8);
            gload_lds16(baseB[t] + kt, Bs + (size_t)(wv * 128 + t * 64) * 8);
        }
        __syncthreads();

        short8 af[4], bfr[4];
#pragma unroll
        for (int i = 0; i < 4; ++i) {
            int lrow = wm * 64 + i * 16 + r;
            int slot = lrow * 4 + (q4 ^ ((lrow >> 1) & 3));
            af[i] = *(const short8*)(As + (size_t)slot * 8);
        }
#pragma unroll
        for (int j = 0; j < 4; ++j) {
            int lrow = wn * 64 + j * 16 + r;
            int slot = lrow * 4 + (q4 ^ ((lrow >> 1) & 3));
            bfr[j] = *(const short8*)(Bs + (size_t)slot * 8);
        }
#pragma unroll
        for (int i = 0; i < 4; ++i)
#pragma unroll
            for (int j = 0; j < 4; ++j)
                acc[i][j] = __builtin_amdgcn_mfma_f32_16x16x32_bf16(af[i], bfr[j], acc[i][j], 0, 0, 0);
    }

    float c0 = 0.f, c1 = 0.f;
#pragma unroll
    for (int i = 0; i < 4; ++i) {
        int lmb = wm * 64 + i * 16 + q4 * 4;
#pragma unroll
        for (int j = 0; j < 4; ++j) {
            int e = n0 + wn * 64 + j * 16 + r;
#pragma unroll
            for (int rg = 0; rg < 4; ++rg) {
                int lm = lmb + rg;
                int m = m0 + lm;
                int ll = m & 2047;
                float hv = embed[(size_t)xs[lm] * 1024 + e];
                float outv = acc[i][j][rg] + hv;
                const float* wfp = Wf + ((size_t)(ll << 10) + e) * 2;
                c0 += outv * wfp[0];
                c1 += outv * wfp[1];
            }
        }
    }
#pragma unroll
    for (int d = 1; d < 64; d <<= 1) {
        c0 += __shfl_xor(c0, d, 64);
        c1 += __shfl_xor(c1, d, 64);
    }
    __syncthreads();
    if (lane == 0) { atomicAdd(&red[0], c0); atomicAdd(&red[1], c1); }
    __syncthreads();
    if (tid == 0) {
        int b = m0 >> 11;
        atomicAdd(&logits[b * 2 + 0], red[0]);
        atomicAdd(&logits[b * 2 + 1], red[1]);
    }
}

// ---------------------------------------------------------------------------
// Loss: sum S slices of [32][2] partials, then -mean_b log_softmax pick.
// ---------------------------------------------------------------------------
__global__ void loss_k(const float* __restrict__ buf, int S,
                       const int* __restrict__ y, const float* __restrict__ bfb,
                       float* __restrict__ out)
{
    __shared__ float sum[64];
    const int t = threadIdx.x;
    float cs = 0.f;
    for (int s = 0; s < S; ++s) cs += buf[s * 64 + t];
    sum[t] = cs;
    __syncthreads();
    float contrib = 0.f;
    if (t < 32) {
        float l0 = sum[t * 2 + 0] + bfb[0];
        float l1 = sum[t * 2 + 1] + bfb[1];
        float mx = fmaxf(l0, l1);
        float lse = mx + logf(expf(l0 - mx) + expf(l1 - mx));
        float chosen = (y[t] == 0) ? l0 : l1;
        contrib = -(chosen - lse) * (1.0f / 32.0f);
    }
#pragma unroll
    for (int d = 1; d < 64; d <<= 1) contrib += __shfl_xor(contrib, d, 64);
    if (t == 0) *out = contrib;
}

// ---------------------------------------------------------------------------
extern "C" void kernel_launch(void* const* d_in, const int* in_sizes, int n_in,
                              void* d_out, int out_size, void* d_ws, size_t ws_size,
                              hipStream_t stream) {
    const int* x      = (const int*)d_in[0];
    const int* y      = (const int*)d_in[1];
    const float* emb  = (const float*)d_in[2];
    const float* Wq   = (const float*)d_in[3];
    const float* Wkv  = (const float*)d_in[4];
    const float* Wo   = (const float*)d_in[5];
    const float* Wf   = (const float*)d_in[6];
    const float* bfb  = (const float*)d_in[7];

    char* ws = (char*)d_ws;
    unsigned short* qkv    = (unsigned short*)ws;                        // 384 MB bf16
    unsigned short* WqkvT  = (unsigned short*)(ws + 402653184);          // [3072][1024] bf16
    unsigned short* Wob    = (unsigned short*)(ws + 408944640);          // 2MB: Wo bf16 (or WoT in fallback)
    float*          logits = (float*)(ws + 411041792);                   // [32][2] fp32 (fallback)
    float*          out    = (float*)d_out;

    const size_t H_OFF  = 411045888ull;
    const size_t H_SIZE = 134217728ull;            // h [65536][1024] bf16
    const size_t G_OFF  = H_OFF + H_SIZE;          // 545263616
    const size_t G_SIZE = 16777216ull;             // G [2048][1024][2] fp32
    const size_t P_OFF  = G_OFF + G_SIZE;          // 562040832
    const size_t P_SIZE = 8192ull;                 // partial [32][64] fp32
    const bool   have_h = (ws_size >= H_OFF + H_SIZE);
    const bool   have_g = (ws_size >= P_OFF + P_SIZE);

    transpose_f32_bf16<<<dim3(32, 32), dim3(32, 8), 0, stream>>>(Wq, WqkvT, 1024, 1024);
    transpose_f32_bf16<<<dim3(64, 32), dim3(32, 8), 0, stream>>>(Wkv, WqkvT + 1024 * 1024, 1024, 2048);

    if (have_g) {
        float* G       = (float*)(ws + G_OFF);
        float* partial = (float*)(ws + P_OFF);
        unsigned short* WfT = qkv;                 // 8MB scratch in qkv region (pre-GEMM1)
        unsigned short* h   = (unsigned short*)(ws + H_OFF);

        zero_n<<<1, 256, 0, stream>>>(partial, 2048);
        cvt_f32_bf16<<<512, 256, 0, stream>>>(Wo, Wob);
        wft_prep<<<2048, 256, 0, stream>>>(Wf, WfT);
        g_gemm<<<dim3(32, 8), 256, 0, stream>>>(Wob, WfT, G);

        gather_h<<<32768, 256, 0, stream>>>(x, emb, h);
        gemm_qkv_dense<<<dim3(24, 512), 256, 0, stream>>>(h, WqkvT, qkv);
        attn<<<8192, 256, 0, stream>>>(qkv);
        logits_fused<<<2048, 256, 0, stream>>>(qkv, h, G, Wf, partial);
        loss_k<<<1, 64, 0, stream>>>(partial, 32, y, bfb, out);
    } else {
        // fallback: old path (WoT transpose + fused gemm_out_logits)
        zero_n<<<1, 256, 0, stream>>>(logits, 64);
        transpose_f32_bf16<<<dim3(32, 32), dim3(32, 8), 0, stream>>>(Wo, Wob, 1024, 1024);
        if (have_h) {
            unsigned short* h = (unsigned short*)(ws + H_OFF);
            gather_h<<<32768, 256, 0, stream>>>(x, emb, h);
            gemm_qkv_dense<<<dim3(24, 512), 256, 0, stream>>>(h, WqkvT, qkv);
        } else {
            gemm_qkv_gather<<<dim3(24, 512), 256, 0, stream>>>(x, emb, WqkvT, qkv);
        }
        attn<<<8192, 256, 0, stream>>>(qkv);
        gemm_out_logits<<<dim3(8, 512), 256, 0, stream>>>(x, emb, qkv, Wob, Wf, logits);
        loss_k<<<1, 64, 0, stream>>>(logits, 1, y, bfb, out);
    }
}